// Round 1
// baseline (1362.426 us; speedup 1.0000x reference)
//
#include <hip/hip_runtime.h>
#include <stdint.h>

// ---------------- problem constants ----------------
#define B_   32
#define T_   256
#define H_   256      // per-direction hidden
#define DB_  768      // input dim
#define DL_  512      // 2*H

// ---------------- workspace layout (bytes) ----------------
#define OFF_DTYPE 0u                          // int: 1 = inputs bf16, 0 = f32
#define OFF_FLAGS 256u                        // [2 dir][8 bw] u32 monotone flags (row stride 128)
#define OFF_DONE  512u                        // [2 dir] u32 done words (fillers poll here)
#define OFF_HBUF  4096u                       // [2 parity][2 dir][32 b][128 u32] = 64 KB
#define OFF_XZ    69632u                      // swizzled xz, per-dir stride 8M elems (16 MB)
#define XZ_DIR_ELEMS 8388608u
#define NEED_CONC (OFF_XZ + 2u*16777216u + 8388608u)
// ---- aliased into the xz region (xz dead after rec) ----
#define OFF_CTX   OFF_XZ                      // context [32][256][512] bf16 = 8 MB
#define OFF_WATT  (OFF_XZ + 8388608u)         // attn weights [32][256][256] bf16 = 4 MB
#define OFF_SQ    (OFF_XZ + 12582912u)        // [8192][10] f32
#define OFF_SK    (OFF_SQ + 327680u)          // [8192][10] f32

typedef __attribute__((ext_vector_type(8))) short bf16x8;
typedef __attribute__((ext_vector_type(4))) float f32x4;
typedef __attribute__((ext_vector_type(4))) uint32_t u32x4;
typedef unsigned short ushort_t;

__device__ __forceinline__ float b2f(ushort_t u){ union{float f; uint32_t i;} v; v.i=((uint32_t)u)<<16; return v.f; }
__device__ __forceinline__ ushort_t f2b(float f){
  union{float ff; uint32_t i;} v; v.ff=f;
  uint32_t r = v.i + 0x7fffu + ((v.i>>16)&1u);
  return (ushort_t)(r>>16);
}
__device__ __forceinline__ float sig_f(float x){ return 1.f/(1.f+__expf(-x)); }
__device__ __forceinline__ float tanh_f(float x){ return 1.f - 2.f/(1.f+__expf(2.f*x)); }

__device__ __forceinline__ bf16x8 load8(const ushort_t* p, size_t idx, int isbf){
  if (isbf) return *(const bf16x8*)(p + idx);
  const float* f = (const float*)p;
  bf16x8 r;
  #pragma unroll
  for (int i=0;i<8;++i) r[i] = (short)f2b(f[idx+i]);
  return r;
}
__device__ __forceinline__ float loadS(const ushort_t* p, size_t idx, int isbf){
  return isbf ? b2f(p[idx]) : ((const float*)p)[idx];
}

// =====================================================================
// dtype probe (R3-verified): votes f32 vs bf16 from exponent stats.
// =====================================================================
__global__ void detect_k(const uint32_t* __restrict__ x, char* __restrict__ ws){
  __shared__ int cnt;
  if (threadIdx.x == 0) cnt = 0;
  __syncthreads();
  int local = 0;
  #pragma unroll
  for (int i=0;i<4;++i){
    uint32_t w = x[threadIdx.x*4 + i];
    uint32_t lo = w & 0xFFFFu;
    int e = (int)((lo >> 7) & 0xFFu);
    if (e >= 118 && e <= 130) local++;
  }
  atomicAdd(&cnt, local);
  __syncthreads();
  if (threadIdx.x == 0) *(int*)(ws + OFF_DTYPE) = (cnt > 512) ? 1 : 0;
}

// =====================================================================
// Generic 128x128-tile bf16 MFMA GEMM (unchanged, R4-R8-verified).
// =====================================================================
template<int MODE>
__global__ __launch_bounds__(256,2) void gemm_k(
    const ushort_t* __restrict__ A0, const ushort_t* __restrict__ A2,
    const ushort_t* __restrict__ Bm, const ushort_t* __restrict__ bias,
    ushort_t* __restrict__ Cout, char* __restrict__ ws,
    int lda, int ldb, int K, int dir, int aIn, int bIn,
    long aOffZ, long bOffZ, long cOffZ)
{
  __shared__ ushort_t As[8192];
  __shared__ ushort_t Bs[8192];
  const int dtf = *(const int*)(ws + OFF_DTYPE);
  const int aBF = aIn ? dtf : 1;
  const int bBF = bIn ? dtf : 1;
  const int tid = threadIdx.x;
  const int l  = tid & 63, wv = tid >> 6;
  const int lc = l & 15,  lh = l >> 4;
  const int m0 = blockIdx.x * 128, n0 = blockIdx.y * 128;
  const int z  = blockIdx.z;
  const ushort_t* Abase = A0 + (size_t)z * aOffZ;
  const ushort_t* Bbase = Bm + (size_t)z * bOffZ;
  const int srow = tid >> 3;
  const int sch  = tid & 7;

  f32x4 acc[4][4];
  #pragma unroll
  for (int i=0;i<4;++i)
    #pragma unroll
    for (int j=0;j<4;++j) acc[i][j] = (f32x4){0.f,0.f,0.f,0.f};

  bf16x8 ra[4], rb[4];
  #pragma unroll
  for (int p=0;p<4;++p){
    int row = p*32 + srow;
    int kk  = (sch ^ (row & 7)) * 8;
    ra[p] = load8(Abase, (size_t)(m0+row)*lda + kk, aBF);
    if (MODE==3){
      int q = p*256 + tid, kr = q>>4, c = q&15;
      rb[p] = load8(Bbase, (size_t)kr*ldb + n0 + c*8, 1);
    } else {
      rb[p] = load8(Bbase, (size_t)(n0+row)*ldb + kk, bBF);
    }
  }

  const int mo = (wv&1)*64, no = (wv>>1)*64;

  for (int k0 = 0; k0 < K; k0 += 64) {
    #pragma unroll
    for (int p=0;p<4;++p){
      int row = p*32 + srow;
      *(bf16x8*)(&As[row*64 + sch*8]) = ra[p];
      if (MODE==3){
        int q = p*256 + tid, kr = q>>4, c = q&15;
        *(bf16x8*)(&Bs[kr*128 + c*8]) = rb[p];
      } else {
        *(bf16x8*)(&Bs[row*64 + sch*8]) = rb[p];
      }
    }
    __syncthreads();
    int k1 = k0 + 64;
    if (k1 < K) {
      #pragma unroll
      for (int p=0;p<4;++p){
        int row = p*32 + srow;
        int kk  = k1 + (sch ^ (row & 7)) * 8;
        if (MODE==2 && k1 >= 512)
          ra[p] = load8(A2, (size_t)(m0+row)*512 + (kk - 512), 1);
        else
          ra[p] = load8(Abase, (size_t)(m0+row)*lda + kk, aBF);
        if (MODE==3){
          int q = p*256 + tid, kr = q>>4, c = q&15;
          rb[p] = load8(Bbase, (size_t)(k1+kr)*ldb + n0 + c*8, 1);
        } else {
          rb[p] = load8(Bbase, (size_t)(n0+row)*ldb + kk, bBF);
        }
      }
    }
    #pragma unroll
    for (int kc=0;kc<2;++kc){
      bf16x8 af[4], bfv[4];
      #pragma unroll
      for (int it=0;it<4;++it){
        int m = mo + it*16 + lc;
        int gc = kc*4 + lh;
        af[it]  = *(const bf16x8*)(&As[m*64 + ((gc ^ (m&7))*8)]);
        int n = no + it*16 + lc;
        if (MODE==3){
          #pragma unroll
          for (int j=0;j<8;++j) bfv[it][j] = (short)Bs[(kc*32 + lh*8 + j)*128 + n];
        } else {
          bfv[it] = *(const bf16x8*)(&Bs[n*64 + ((gc ^ (n&7))*8)]);
        }
      }
      #pragma unroll
      for (int mt=0;mt<4;++mt)
        #pragma unroll
        for (int nt=0;nt<4;++nt)
          acc[mt][nt] = __builtin_amdgcn_mfma_f32_16x16x32_bf16(af[mt], bfv[nt], acc[mt][nt], 0,0,0);
    }
    __syncthreads();
  }

  ushort_t* xzsw = (ushort_t*)(ws + OFF_XZ);
  #pragma unroll
  for (int mt=0;mt<4;++mt){
    #pragma unroll
    for (int nt=0;nt<4;++nt){
      #pragma unroll
      for (int r=0;r<4;++r){
        int m = m0 + mo + mt*16 + lh*4 + r;
        int n = n0 + no + nt*16 + lc;
        float v = acc[mt][nt][r];
        if (MODE==0){
          v += loadS(bias, n, bBF);
          int b = m >> 8, t = m & 255;
          int ts = dir ? (255 - t) : t;
          int q = n >> 8, jm = n & 255;
          int w = jm >> 6, jj = jm & 63, wvv = jj >> 4, colj = jj & 15;
          int lane = ((b >> 2) & 3)*16 + colj;
          int idx  = (b >> 4)*16 + q*4 + (b & 3);
          size_t e = (((size_t)(w*4 + wvv)*256 + ts)*2048) + (size_t)lane*32 + idx;
          xzsw[e + (size_t)cOffZ] = f2b(v);
        } else if (MODE==3){
          Cout[(size_t)z*cOffZ + (size_t)m*DL_ + n] = f2b(v);
        } else {
          v += loadS(bias, n, bBF);
          if (dtf) Cout[(size_t)m*DL_ + n] = f2b(v);
          else     ((float*)Cout)[(size_t)m*DL_ + n] = v;
        }
      }
    }
  }
}

// =====================================================================
// Persistent BiLSTM recurrence, v6.
//   * Handoff: producers store h (relaxed agent, LLC) -> waitcnt ->
//     barrier -> tid0 stores a MONOTONE per-producer flag word
//     flags[d][bw] = t+1 (no RMW, no serialization at the LLC bank).
//     Consumers: ALL lanes min-poll the 8-word flag row (relaxed agent
//     loads, one line) until min >= t, then 8 PLAIN buffer_load_dwordx4
//     with CPol sc0|sc1 (LLC read). No consumer-side barrier needed.
//   * DVFS fillers: blocks >= nReal skip the LSTM and spin independent
//     FMA chains on the remaining ~240 CUs, polling a dedicated done
//     word (separate cache line). The recurrence is latency-bound at
//     ~2900 shader cycles/step; measured 3.95 us/step implies SCLK was
//     ~740 MHz (chip looked idle). Fillers hold the activity signal
//     high so SCLK stays up; they exit within one spin chunk of done.
// =====================================================================
__global__ __launch_bounds__(256,1) void rec_k(
    const ushort_t* __restrict__ Whh_f, const ushort_t* __restrict__ Whh_b,
    char* __restrict__ ws, ushort_t* __restrict__ hist,
    int dParam, long xzDirStride, int nReal)
{
  __shared__ ushort_t wlds[32768];   // 64 KB: 64 frags x 1 KB
  const int bid = (int)blockIdx.x;
  const int tid = threadIdx.x;
  uint32_t* done = (uint32_t*)(ws + OFF_DONE);

  if (bid >= nReal) {
    // ---------------- DVFS filler ----------------
    const uint32_t needMask = (nReal == 16) ? 3u : (1u << dParam);
    float a = 1.0f + (float)tid * 1e-3f, b = 2.0f, c = 3.0f, e = 4.0f;
    for (;;) {
      uint32_t g0 = __hip_atomic_load(done + 0, __ATOMIC_RELAXED, __HIP_MEMORY_SCOPE_AGENT);
      uint32_t g1 = __hip_atomic_load(done + 1, __ATOMIC_RELAXED, __HIP_MEMORY_SCOPE_AGENT);
      uint32_t got = (g0 ? 1u : 0u) | (g1 ? 2u : 0u);
      if ((got & needMask) == needMask) break;
      #pragma unroll
      for (int i = 0; i < 256; ++i) {
        a = __builtin_fmaf(a, 1.0000001f, 1e-7f);
        b = __builtin_fmaf(b, 0.9999999f, 1e-7f);
        c = __builtin_fmaf(c, 1.0000002f, 1e-7f);
        e = __builtin_fmaf(e, 0.9999998f, 1e-7f);
      }
      asm volatile("" : "+v"(a), "+v"(b), "+v"(c), "+v"(e));
    }
    return;
  }

  const int d  = (nReal == 16) ? (bid >> 3) : dParam;
  const int bw = bid & 7;
  const int wv = tid >> 6, l = tid & 63;
  const int lc = l & 15, lh = l >> 4;
  const int bh = wv & 1, hh = wv >> 1;
  const int dtf = *(const int*)(ws + OFF_DTYPE);

  uint32_t* frow  = (uint32_t*)(ws + OFF_FLAGS + (size_t)d * 128);  // 8 monotone words
  uint32_t* hbuf  = (uint32_t*)(ws + OFF_HBUF);                     // u32-packed bf16 pairs
  const ushort_t* xz = (const ushort_t*)(ws + OFF_XZ) + (size_t)d * xzDirStride;
  const ushort_t* Whh = d ? Whh_b : Whh_f;

  const int jj = bw*32 + hh*16 + lc;    // this lane's hidden unit
  const int g  = bw*2 + hh;             // hidden-16-group for xz layout

  // ---- stage this block's 64 KB weight slice into LDS (R8-proven) ----
  #pragma unroll
  for (int i=0;i<16;++i){
    int f   = wv*16 + i;
    int fhh = f >> 5, fnt = (f >> 3) & 3, fkc = f & 7;
    int row = fnt*256 + bw*32 + fhh*16 + lc;
    bf16x8 v = load8(Whh, (size_t)row*256 + fkc*32 + lh*8, dtf);
    *(bf16x8*)(&wlds[f*512 + l*8]) = v;
  }
  __syncthreads();
  const int wbase = (hh*4)*8;   // this wave's fragment group base

  float cst[4] = {0.f, 0.f, 0.f, 0.f};

  const ushort_t* xzb = xz + (size_t)g*256*2048 + (size_t)l*32 + bh*16;
  const int hOffByte = (bh*16 + lc)*512 + lh*16;   // per-lane h-load base (bytes)

  for (int t=0; t<T_; ++t){
    // prefetch xz[t] (plain cached loads — L2 stays warm, no invalidates)
    bf16x8 xzv[2];
    xzv[0] = *(const bf16x8*)(xzb + (size_t)t*2048);
    xzv[1] = *(const bf16x8*)(xzb + (size_t)t*2048 + 8);

    f32x4 acc[4];
    #pragma unroll
    for (int j=0;j<4;++j) acc[j] = (f32x4){0.f,0.f,0.f,0.f};

    if (t > 0){
      // all-lane min-poll of the 8 producer flags (one cache line)
      const uint32_t tv = (uint32_t)t;
      for (;;){
        uint32_t f0 = __hip_atomic_load(frow+0, __ATOMIC_RELAXED, __HIP_MEMORY_SCOPE_AGENT);
        uint32_t f1 = __hip_atomic_load(frow+1, __ATOMIC_RELAXED, __HIP_MEMORY_SCOPE_AGENT);
        uint32_t f2 = __hip_atomic_load(frow+2, __ATOMIC_RELAXED, __HIP_MEMORY_SCOPE_AGENT);
        uint32_t f3 = __hip_atomic_load(frow+3, __ATOMIC_RELAXED, __HIP_MEMORY_SCOPE_AGENT);
        uint32_t f4 = __hip_atomic_load(frow+4, __ATOMIC_RELAXED, __HIP_MEMORY_SCOPE_AGENT);
        uint32_t f5 = __hip_atomic_load(frow+5, __ATOMIC_RELAXED, __HIP_MEMORY_SCOPE_AGENT);
        uint32_t f6 = __hip_atomic_load(frow+6, __ATOMIC_RELAXED, __HIP_MEMORY_SCOPE_AGENT);
        uint32_t f7 = __hip_atomic_load(frow+7, __ATOMIC_RELAXED, __HIP_MEMORY_SCOPE_AGENT);
        uint32_t m0 = f0 < f1 ? f0 : f1;
        uint32_t m1 = f2 < f3 ? f2 : f3;
        uint32_t m2 = f4 < f5 ? f4 : f5;
        uint32_t m3 = f6 < f7 ? f6 : f7;
        uint32_t ma = m0 < m1 ? m0 : m1;
        uint32_t mb = m2 < m3 ? m2 : m3;
        if ((ma < mb ? ma : mb) >= tv) break;
      }

      const uint32_t* hb = hbuf + (size_t)(((t-1)&1)*2 + d)*(B_*H_/2);
      __amdgpu_buffer_rsrc_t rs =
        __builtin_amdgcn_make_buffer_rsrc((void*)hb, (short)0, 0xFFFFFFFFu, 0x00020000);
      u32x4 hreg[8];
      #pragma unroll
      for (int kc=0;kc<8;++kc)
        hreg[kc] = __builtin_bit_cast(u32x4,
          __builtin_amdgcn_raw_buffer_load_b128(rs, hOffByte + kc*64, 0, /*sc0|sc1*/17));

      #pragma unroll
      for (int kc=0;kc<8;++kc){
        bf16x8 a = __builtin_bit_cast(bf16x8, hreg[kc]);
        #pragma unroll
        for (int nt=0;nt<4;++nt){
          bf16x8 wfrag = *(const bf16x8*)(&wlds[(wbase + nt*8 + kc)*512 + l*8]);
          acc[nt] = __builtin_amdgcn_mfma_f32_16x16x32_bf16(a, wfrag, acc[nt], 0,0,0);
        }
      }
    }

    const int ts = d ? (255 - t) : t;
    uint32_t* hb_out = hbuf + (size_t)((t&1)*2 + d)*(B_*H_/2);
    uint32_t* histw  = (uint32_t*)hist;
    #pragma unroll
    for (int r=0;r<4;++r){
      float zi = acc[0][r] + b2f((ushort_t)xzv[(r+0 )>>3][(r+0 )&7]);
      float zf = acc[1][r] + b2f((ushort_t)xzv[(r+4 )>>3][(r+4 )&7]);
      float zg = acc[2][r] + b2f((ushort_t)xzv[(r+8 )>>3][(r+8 )&7]);
      float zo = acc[3][r] + b2f((ushort_t)xzv[(r+12)>>3][(r+12)&7]);
      float ig = sig_f(zi), fg = sig_f(zf), gg = tanh_f(zg), og = sig_f(zo);
      float c = fg * cst[r] + ig * gg;
      cst[r] = c;
      float h = og * tanh_f(c);
      ushort_t h16 = f2b(h);
      int b = bh*16 + lh*4 + r;
      uint32_t mine = (uint32_t)h16;
      uint32_t partner = (uint32_t)__shfl_xor((int)mine, 1);
      if ((lc & 1) == 0){
        uint32_t packed = mine | (partner << 16);
        __hip_atomic_store(hb_out + (size_t)b*128 + (jj>>1), packed,
                           __ATOMIC_RELAXED, __HIP_MEMORY_SCOPE_AGENT);
        histw[(((size_t)(b*256 + ts))*512 + d*256 + jj) >> 1] = packed;  // plain cached
      }
    }
    __builtin_amdgcn_s_waitcnt(0);   // drain stores before flagging
    __syncthreads();
    if (tid == 0)
      __hip_atomic_store(frow + bw, (uint32_t)(t+1),
                         __ATOMIC_RELAXED, __HIP_MEMORY_SCOPE_AGENT);
  }

  if (tid == 0 && bw == 0)
    __hip_atomic_store(done + d, 1u, __ATOMIC_RELAXED, __HIP_MEMORY_SCOPE_AGENT);
}

// =====================================================================
// C1: sq[m][x] = h[m]·W1[x][0:512], sk[m][x] = h[m]·W1[x][512:1024]
// =====================================================================
__global__ __launch_bounds__(256) void c1_k(char* __restrict__ ws, const ushort_t* __restrict__ W1,
                                            const ushort_t* __restrict__ hist)
{
  float* sq = (float*)(ws + OFF_SQ);
  float* sk = (float*)(ws + OFF_SK);
  const int dtf = *(const int*)(ws + OFF_DTYPE);
  int tid = threadIdx.x; int wv = tid>>6, l = tid&63;
  int row = blockIdx.x*4 + wv;
  bf16x8 hv = *(const bf16x8*)(hist + (size_t)row*512 + l*8);
  float hf[8];
  #pragma unroll
  for (int i=0;i<8;++i) hf[i] = b2f((ushort_t)hv[i]);
  #pragma unroll
  for (int x=0;x<10;++x){
    bf16x8 qv = load8(W1, (size_t)x*1024 + l*8, dtf);
    bf16x8 kv = load8(W1, (size_t)x*1024 + 512 + l*8, dtf);
    float pq=0.f, pk=0.f;
    #pragma unroll
    for (int i=0;i<8;++i){ pq += hf[i]*b2f((ushort_t)qv[i]); pk += hf[i]*b2f((ushort_t)kv[i]); }
    #pragma unroll
    for (int off=32; off>0; off>>=1){ pq += __shfl_xor(pq, off, 64); pk += __shfl_xor(pk, off, 64); }
    if (l == 0){ sq[row*10 + x] = pq; sk[row*10 + x] = pk; }
  }
}

// =====================================================================
// C2: a = sum_x tanh(sq+sk)*W2[x]; masked softmax -> bf16 watt
// =====================================================================
__global__ __launch_bounds__(256) void c2_k(char* __restrict__ ws, const ushort_t* __restrict__ W2,
                                            const ushort_t* __restrict__ mask)
{
  const float* sq = (const float*)(ws + OFF_SQ);
  const float* sk = (const float*)(ws + OFF_SK);
  ushort_t* watt = (ushort_t*)(ws + OFF_WATT);
  const int dtf = *(const int*)(ws + OFF_DTYPE);
  int tid = threadIdx.x; int wv = tid>>6, l = tid&63;
  int bq = blockIdx.x*4 + wv;
  int b  = bq >> 8;
  float sqv[10], w2v[10];
  #pragma unroll
  for (int x=0;x<10;++x){ sqv[x] = sq[(size_t)bq*10+x]; w2v[x] = loadS(W2, x, dtf); }
  float a[4];
  #pragma unroll
  for (int kk=0;kk<4;++kk){
    int k = kk*64 + l;
    const float* skp = sk + ((size_t)b*256 + k)*10;
    float s = 0.f;
    #pragma unroll
    for (int x=0;x<10;++x) s += tanh_f(sqv[x] + skp[x]) * w2v[x];
    float mval = loadS(mask, (size_t)b*256 + k, dtf);
    a[kk] = (mval == 0.f) ? -1e30f : s;
  }
  float mx = fmaxf(fmaxf(a[0],a[1]), fmaxf(a[2],a[3]));
  #pragma unroll
  for (int off=32; off>0; off>>=1) mx = fmaxf(mx, __shfl_xor(mx, off, 64));
  float e[4], ssum=0.f;
  #pragma unroll
  for (int kk=0;kk<4;++kk){ e[kk] = __expf(a[kk]-mx); ssum += e[kk]; }
  #pragma unroll
  for (int off=32; off>0; off>>=1) ssum += __shfl_xor(ssum, off, 64);
  float inv = 1.f/ssum;
  #pragma unroll
  for (int kk=0;kk<4;++kk) watt[(size_t)bq*256 + kk*64 + l] = f2b(e[kk]*inv);
}

// =====================================================================
extern "C" void kernel_launch(void* const* d_in, const int* in_sizes, int n_in,
                              void* d_out, int out_size, void* d_ws, size_t ws_size,
                              hipStream_t stream)
{
  const ushort_t* x     = (const ushort_t*)d_in[0];
  const ushort_t* mask  = (const ushort_t*)d_in[1];
  const ushort_t* Wih_f = (const ushort_t*)d_in[2];
  const ushort_t* Whh_f = (const ushort_t*)d_in[3];
  const ushort_t* b_f   = (const ushort_t*)d_in[4];
  const ushort_t* Wih_b = (const ushort_t*)d_in[5];
  const ushort_t* Whh_b = (const ushort_t*)d_in[6];
  const ushort_t* b_b   = (const ushort_t*)d_in[7];
  const ushort_t* W1    = (const ushort_t*)d_in[8];
  const ushort_t* W2    = (const ushort_t*)d_in[9];
  const ushort_t* W3    = (const ushort_t*)d_in[10];
  const ushort_t* b3    = (const ushort_t*)d_in[11];
  ushort_t* out = (ushort_t*)d_out;
  char* ws = (char*)d_ws;

  const bool conc = ws_size >= (size_t)NEED_CONC;
  ushort_t* hist = (ushort_t*)(ws + OFF_XZ + (conc ? 33554432u : 16777216u));

  hipMemsetAsync(ws, 0, 4096, stream);           // dtype flag + sync/done flags
  detect_k<<<dim3(1), dim3(256), 0, stream>>>((const uint32_t*)d_in[0], ws);

  dim3 blk(256);
  if (conc){
    gemm_k<0><<<dim3(64,8,1), blk, 0, stream>>>(x, nullptr, Wih_f, b_f, nullptr, ws,
                                                DB_, DB_, DB_, 0, 1, 1, 0,0, 0L);
    gemm_k<0><<<dim3(64,8,1), blk, 0, stream>>>(x, nullptr, Wih_b, b_b, nullptr, ws,
                                                DB_, DB_, DB_, 1, 1, 1, 0,0, (long)XZ_DIR_ELEMS);
    rec_k<<<dim3(256), blk, 0, stream>>>(Whh_f, Whh_b, ws, hist, 0, (long)XZ_DIR_ELEMS, 16);
  } else {
    gemm_k<0><<<dim3(64,8,1), blk, 0, stream>>>(x, nullptr, Wih_f, b_f, nullptr, ws,
                                                DB_, DB_, DB_, 0, 1, 1, 0,0, 0L);
    rec_k<<<dim3(248), blk, 0, stream>>>(Whh_f, Whh_b, ws, hist, 0, 0L, 8);
    gemm_k<0><<<dim3(64,8,1), blk, 0, stream>>>(x, nullptr, Wih_b, b_b, nullptr, ws,
                                                DB_, DB_, DB_, 1, 1, 1, 0,0, 0L);
    rec_k<<<dim3(248), blk, 0, stream>>>(Whh_f, Whh_b, ws, hist, 1, 0L, 8);
  }
  // attention
  c1_k<<<dim3(2048), blk, 0, stream>>>(ws, W1, hist);
  c2_k<<<dim3(2048), blk, 0, stream>>>(ws, W2, mask);
  // context = watt @ h (per batch), B row-major from hist
  gemm_k<3><<<dim3(2,4,32), blk, 0, stream>>>((ushort_t*)(ws+OFF_WATT), nullptr,
                                              hist, nullptr,
                                              (ushort_t*)(ws+OFF_CTX), ws,
                                              256, 512, 256, 0, 0, 0,
                                              65536L, 131072L, 131072L);
  // y = concat(h, ctx) @ W3^T + b3 -> d_out (dtype-matched store)
  gemm_k<2><<<dim3(64,4,1), blk, 0, stream>>>(hist, (ushort_t*)(ws+OFF_CTX),
                                              W3, b3, out, ws,
                                              512, 1024, 1024, 0, 0, 1, 0,0, 0L);
}